// Round 2
// baseline (84.653 us; speedup 1.0000x reference)
//
#include <hip/hip_runtime.h>

// Fused GCNConv(16->20, 85 nodes, 600 edges) + reshape(100,17) + ReLU + Linear(17,7).
// Single block, single launch: all stage dependencies resolved with __syncthreads,
// all intermediates in LDS (~22 KB). Problem is launch-overhead-bound (~51k MACs).

#define N_NODES 85
#define N_EDGES 600
#define F_IN    16
#define F_OUT   20
#define XW_ELEMS (N_NODES * F_OUT)   // 1700 == 100*17
#define OUT_ROWS 100
#define OUT_COLS 7
#define FC_K     17

__global__ __launch_bounds__(512) void gcn_fused_kernel(
    const float* __restrict__ x,          // [85,16]
    const int*   __restrict__ edge_index, // [2,600] (int32 per harness contract)
    const float* __restrict__ W_gcn,      // [16,20]
    const float* __restrict__ b_gcn,      // [20]
    const float* __restrict__ W_fc,       // [17,7]
    const float* __restrict__ b_fc,       // [7]
    float*       __restrict__ out)        // [100,7]
{
    __shared__ float s_x   [N_NODES * F_IN];   // 1360
    __shared__ float s_Wg  [F_IN * F_OUT];     // 320
    __shared__ float s_xw  [XW_ELEMS];         // 1700
    __shared__ float s_deg [N_NODES];
    __shared__ float s_dinv[N_NODES];
    __shared__ float s_agg [XW_ELEMS];         // 1700
    __shared__ float s_norm[N_EDGES];          // 600
    __shared__ int   s_row [N_EDGES];
    __shared__ int   s_col [N_EDGES];
    __shared__ float s_Wfc [FC_K * OUT_COLS];  // 119
    __shared__ float s_bfc [OUT_COLS];
    __shared__ float s_bg  [F_OUT];

    const int t  = threadIdx.x;
    const int NT = blockDim.x;

    // ---- stage 0: load everything into LDS ----
    for (int i = t; i < N_NODES * F_IN; i += NT) s_x[i]  = x[i];
    for (int i = t; i < F_IN * F_OUT;   i += NT) s_Wg[i] = W_gcn[i];
    for (int i = t; i < N_EDGES; i += NT) {
        s_row[i] = edge_index[i];             // sources
        s_col[i] = edge_index[N_EDGES + i];   // targets (aggregation index)
    }
    for (int i = t; i < FC_K * OUT_COLS; i += NT) s_Wfc[i] = W_fc[i];
    if (t < OUT_COLS) s_bfc[t] = b_fc[t];
    if (t < F_OUT)    s_bg[t]  = b_gcn[t];
    for (int i = t; i < N_NODES; i += NT) s_deg[i] = 1.0f;  // self-loop
    __syncthreads();

    // ---- stage 1: degree (atomics) + xW (independent, overlapped) ----
    for (int e = t; e < N_EDGES; e += NT) atomicAdd(&s_deg[s_col[e]], 1.0f);
    for (int i = t; i < XW_ELEMS; i += NT) {
        const int n = i / F_OUT, f = i % F_OUT;
        float acc = 0.0f;
        #pragma unroll
        for (int k = 0; k < F_IN; ++k) acc += s_x[n * F_IN + k] * s_Wg[k * F_OUT + f];
        s_xw[i] = acc;
    }
    __syncthreads();

    // ---- stage 2: dinv = rsqrt(deg) (deg >= 1 always, self-loop) ----
    for (int i = t; i < N_NODES; i += NT) s_dinv[i] = rsqrtf(s_deg[i]);
    __syncthreads();

    // ---- stage 3: per-edge norm + agg init with self-loop term ----
    for (int e = t; e < N_EDGES; e += NT)
        s_norm[e] = s_dinv[s_row[e]] * s_dinv[s_col[e]];
    for (int i = t; i < XW_ELEMS; i += NT) {
        const int n = i / F_OUT;
        s_agg[i] = s_dinv[n] * s_dinv[n] * s_xw[i];
    }
    __syncthreads();

    // ---- stage 4: edge scatter, parallel over (edge, feature) ----
    for (int i = t; i < N_EDGES * F_OUT; i += NT) {
        const int e = i / F_OUT, f = i % F_OUT;
        atomicAdd(&s_agg[s_col[e] * F_OUT + f],
                  s_norm[e] * s_xw[s_row[e] * F_OUT + f]);
    }
    __syncthreads();

    // ---- stage 5: x1 = agg + b_gcn, ReLU on the flat (100,17) view ----
    for (int i = t; i < XW_ELEMS; i += NT) {
        const float v = s_agg[i] + s_bg[i % F_OUT];
        s_agg[i] = v > 0.0f ? v : 0.0f;
    }
    __syncthreads();

    // ---- stage 6: Linear(17,7): out[r][c] = sum_k h[r*17+k] * W_fc[k][c] + b_fc[c] ----
    for (int i = t; i < OUT_ROWS * OUT_COLS; i += NT) {
        const int r = i / OUT_COLS, c = i % OUT_COLS;
        float acc = s_bfc[c];
        #pragma unroll
        for (int k = 0; k < FC_K; ++k)
            acc += s_agg[r * FC_K + k] * s_Wfc[k * OUT_COLS + c];
        out[i] = acc;
    }
}

extern "C" void kernel_launch(void* const* d_in, const int* in_sizes, int n_in,
                              void* d_out, int out_size, void* d_ws, size_t ws_size,
                              hipStream_t stream) {
    const float* x          = (const float*)d_in[0];
    const int*   edge_index = (const int*)  d_in[1];
    const float* W_gcn      = (const float*)d_in[2];
    const float* b_gcn      = (const float*)d_in[3];
    const float* W_fc       = (const float*)d_in[4];
    const float* b_fc       = (const float*)d_in[5];
    float*       out        = (float*)d_out;

    gcn_fused_kernel<<<1, 512, 0, stream>>>(x, edge_index, W_gcn, b_gcn, W_fc, b_fc, out);
}

// Round 4
// 83.808 us; speedup vs baseline: 1.0101x; 1.0101x over previous
//
#include <hip/hip_runtime.h>

// Fused GCNConv(16->20, 85 nodes, 600 edges) + reshape(100,17) + ReLU + Linear(17,7).
// Single block, single launch; all intermediates in LDS (~28 KB).
// Round-3 changes vs round-2: 7 barriers -> 4 (dinv folded into norm via
// rsqrt(deg_r*deg_c); bias+ReLU folded into the FC read), float4/int4 staging.

#define N_NODES 85
#define N_EDGES 600
#define F_IN    16
#define F_OUT   20
#define XW_ELEMS (N_NODES * F_OUT)   // 1700 == 100*17
#define OUT_ROWS 100
#define OUT_COLS 7
#define FC_K     17

__global__ __launch_bounds__(512) void gcn_fused_kernel(
    const float* __restrict__ x,          // [85,16]
    const int*   __restrict__ edge_index, // [2,600]
    const float* __restrict__ W_gcn,      // [16,20]
    const float* __restrict__ b_gcn,      // [20]
    const float* __restrict__ W_fc,       // [17,7]
    const float* __restrict__ b_fc,       // [7]
    float*       __restrict__ out)        // [100,7]
{
    __shared__ __align__(16) float s_x  [N_NODES * F_IN];   // 1360
    __shared__ __align__(16) float s_Wg [F_IN * F_OUT];     // 320
    __shared__ float s_xw  [XW_ELEMS];                      // 1700
    __shared__ float s_agg [XW_ELEMS];                      // 1700
    __shared__ float s_deg [N_NODES];
    __shared__ float s_norm[N_EDGES];
    __shared__ int   s_row [N_EDGES];
    __shared__ int   s_col [N_EDGES];
    __shared__ float s_Wfc [FC_K * OUT_COLS];               // 119
    __shared__ float s_bfc [OUT_COLS];
    __shared__ float s_bg  [F_OUT];

    const int t  = threadIdx.x;
    const int NT = 512;

    // ---- stage 0: vectorized staging ----
    {
        const float4* x4 = (const float4*)x;          // 1360/4 = 340
        float4* sx4 = (float4*)s_x;
        for (int i = t; i < (N_NODES * F_IN) / 4; i += NT) sx4[i] = x4[i];

        const float4* w4 = (const float4*)W_gcn;      // 320/4 = 80
        float4* sw4 = (float4*)s_Wg;
        if (t < (F_IN * F_OUT) / 4) sw4[t] = w4[t];

        const int4* e4 = (const int4*)edge_index;     // 1200/4 = 300; first 150 = rows
        for (int i = t; i < (2 * N_EDGES) / 4; i += NT) {
            const int4 v = e4[i];
            int* dst = (i < N_EDGES / 4) ? &s_row[i * 4] : &s_col[(i - N_EDGES / 4) * 4];
            dst[0] = v.x; dst[1] = v.y; dst[2] = v.z; dst[3] = v.w;
        }

        if (t < FC_K * OUT_COLS) s_Wfc[t] = W_fc[t];
        if (t < OUT_COLS)        s_bfc[t] = b_fc[t];
        if (t < F_OUT)           s_bg[t]  = b_gcn[t];
        if (t < N_NODES)         s_deg[t] = 1.0f;     // self-loop
    }
    __syncthreads();

    // ---- stage 1: degree (LDS atomics) + xW (independent, overlapped) ----
    for (int e = t; e < N_EDGES; e += NT) atomicAdd(&s_deg[s_col[e]], 1.0f);
    for (int i = t; i < XW_ELEMS; i += NT) {
        const int n = i / F_OUT, f = i - n * F_OUT;
        float acc = 0.0f;
        #pragma unroll
        for (int k = 0; k < F_IN; ++k) acc += s_x[n * F_IN + k] * s_Wg[k * F_OUT + f];
        s_xw[i] = acc;
    }
    __syncthreads();

    // ---- stage 2: per-edge norm = rsqrt(deg_r * deg_c); agg init = xw/deg (self-loop) ----
    for (int e = t; e < N_EDGES; e += NT)
        s_norm[e] = rsqrtf(s_deg[s_row[e]] * s_deg[s_col[e]]);
    for (int i = t; i < XW_ELEMS; i += NT) {
        const int n = i / F_OUT;
        s_agg[i] = s_xw[i] / s_deg[n];
    }
    __syncthreads();

    // ---- stage 3: edge scatter over (edge, feature) ----
    for (int i = t; i < N_EDGES * F_OUT; i += NT) {
        const int e = i / F_OUT, f = i - e * F_OUT;
        atomicAdd(&s_agg[s_col[e] * F_OUT + f],
                  s_norm[e] * s_xw[s_row[e] * F_OUT + f]);
    }
    __syncthreads();

    // ---- stage 4: FC with inline bias+ReLU on the flat (100,17) view ----
    // h[r*17+k] = relu(agg[r*17+k] + b_gcn[(r*17+k) % 20])
    for (int i = t; i < OUT_ROWS * OUT_COLS; i += NT) {
        const int r = i / OUT_COLS, c = i - r * OUT_COLS;
        const int flat0 = r * FC_K;
        const int base  = flat0 % F_OUT;              // one modulo per output
        float acc = s_bfc[c];
        #pragma unroll
        for (int k = 0; k < FC_K; ++k) {
            int bidx = base + k;                      // < 36: single conditional wrap
            if (bidx >= F_OUT) bidx -= F_OUT;
            float v = s_agg[flat0 + k] + s_bg[bidx];
            v = v > 0.0f ? v : 0.0f;
            acc += v * s_Wfc[k * OUT_COLS + c];
        }
        out[i] = acc;
    }
}

extern "C" void kernel_launch(void* const* d_in, const int* in_sizes, int n_in,
                              void* d_out, int out_size, void* d_ws, size_t ws_size,
                              hipStream_t stream) {
    const float* x          = (const float*)d_in[0];
    const int*   edge_index = (const int*)  d_in[1];
    const float* W_gcn      = (const float*)d_in[2];
    const float* b_gcn      = (const float*)d_in[3];
    const float* W_fc       = (const float*)d_in[4];
    const float* b_fc       = (const float*)d_in[5];
    float*       out        = (float*)d_out;

    gcn_fused_kernel<<<1, 512, 0, stream>>>(x, edge_index, W_gcn, b_gcn, W_fc, b_fc, out);
}